// Round 15
// baseline (277.488 us; speedup 1.0000x reference)
//
#include <hip/hip_runtime.h>
#include <hip/hip_bf16.h>

#define B_    32
#define SDEC  128
#define SENC  128
#define V_    32000
#define E_    200
#define H_    128
#define G3    384   // 3*H

typedef __attribute__((ext_vector_type(8))) short bf16x8;
typedef __attribute__((ext_vector_type(4))) float f32x4;
typedef __attribute__((ext_vector_type(2))) float f32x2;

#define GLOBAL_AS __attribute__((address_space(1)))
#define LDS_AS    __attribute__((address_space(3)))

__device__ __forceinline__ float fast_sigmoid(float x) {
  return 1.f / (1.f + __expf(-x));
}
__device__ __forceinline__ float fast_tanh(float x) {
  float e2 = __expf(2.f * x);
  return 1.f - 2.f / (e2 + 1.f);
}
// butterfly sum over each aligned 4-lane quad, pure VALU (DPP quad_perm)
__device__ __forceinline__ float quad_reduce(float x) {
  int i = __builtin_bit_cast(int, x);
  int a = __builtin_amdgcn_mov_dpp(i, 0xB1, 0xF, 0xF, true);  // xor 1
  float s = x + __builtin_bit_cast(float, a);
  int j = __builtin_bit_cast(int, s);
  int c = __builtin_amdgcn_mov_dpp(j, 0x4E, 0xF, 0xF, true);  // xor 2
  return s + __builtin_bit_cast(float, c);
}

// ---------------------------------------------------------------------------
// Kernel 1: x = emb[seq]; xg = x @ w_ih^T + b_ih   -> xg [4096][384] f32
// ---------------------------------------------------------------------------
__global__ __launch_bounds__(192) void k_embed_proj(
    const int* __restrict__ seq, const float* __restrict__ emb,
    const float* __restrict__ w_ih, const float* __restrict__ b_ih,
    float* __restrict__ xg) {
  __shared__ __align__(16) float xs[16][E_];
  __shared__ int sidx[16];
  const int r0 = blockIdx.x * 16;
  const int t = threadIdx.x;
  if (t < 16) sidx[t] = seq[r0 + t];
  __syncthreads();
  for (int i = t; i < 800; i += 192) {
    int r = i / 50, c = i - r * 50;
    *(float4*)&xs[r][c * 4] =
        *(const float4*)(emb + (size_t)sidx[r] * E_ + c * 4);
  }
  __syncthreads();
  const int g0 = t, g1 = t + 192;
  float a0[16], a1[16];
#pragma unroll
  for (int r = 0; r < 16; r++) { a0[r] = 0.f; a1[r] = 0.f; }
  const float* w0 = w_ih + (size_t)g0 * E_;
  const float* w1 = w_ih + (size_t)g1 * E_;
  for (int k = 0; k < E_; k += 4) {
    float4 wv0 = *(const float4*)(w0 + k);
    float4 wv1 = *(const float4*)(w1 + k);
#pragma unroll
    for (int r = 0; r < 16; r++) {
      float4 xv = *(const float4*)&xs[r][k];
      a0[r] += wv0.x * xv.x + wv0.y * xv.y + wv0.z * xv.z + wv0.w * xv.w;
      a1[r] += wv1.x * xv.x + wv1.y * xv.y + wv1.z * xv.z + wv1.w * xv.w;
    }
  }
  const float b0 = b_ih[g0], b1 = b_ih[g1];
#pragma unroll
  for (int r = 0; r < 16; r++) {
    xg[(size_t)(r0 + r) * G3 + g0] = a0[r] + b0;
    xg[(size_t)(r0 + r) * G3 + g1] = a1[r] + b1;
  }
}

// ---------------------------------------------------------------------------
// Kernel 2: blocks 0..31  : GRU scan + fused MFMA attention (one batch each)
//           blocks 32..531: w_out f32->bf16, 4 ILP chunks each
// R15 change (single variable vs R14): cat_bf global stores are accumulated
// in registers (8 steps, static idx) and burst-written once per 8 steps —
// removes per-step store from the vmcnt FIFO path (waiting for a newer load
// completes all older VMEM ops, incl. the store-ack).
// ---------------------------------------------------------------------------
__global__ __launch_bounds__(512) void k_gru_attn_cvt(
    const float* __restrict__ xg, const float* __restrict__ h0,
    const float* __restrict__ w_hh, const float* __restrict__ b_hh,
    const float* __restrict__ hs, __hip_bfloat16* __restrict__ cat_bf,
    float* __restrict__ state_out, float* __restrict__ attw_out,
    const float* __restrict__ w_out, __hip_bfloat16* __restrict__ wout_bf) {
  if (blockIdx.x >= 32) {
    const int base = (blockIdx.x - 32) * 4;
#pragma unroll
    for (int j = 0; j < 4; j++) {
      int idx = ((base + j) * 512 + threadIdx.x) * 8;
      float4 a = *(const float4*)(w_out + idx);
      float4 c = *(const float4*)(w_out + idx + 4);
      union { __hip_bfloat16 h[8]; uint4 v; } p;
      p.h[0] = __float2bfloat16(a.x); p.h[1] = __float2bfloat16(a.y);
      p.h[2] = __float2bfloat16(a.z); p.h[3] = __float2bfloat16(a.w);
      p.h[4] = __float2bfloat16(c.x); p.h[5] = __float2bfloat16(c.y);
      p.h[6] = __float2bfloat16(c.z); p.h[7] = __float2bfloat16(c.w);
      *(uint4*)(wout_bf + idx) = p.v;
    }
    return;
  }

  __shared__ __hip_bfloat16 ctb[128][128];  // GRU out (scan) -> P (phase 4)
  __shared__ __hip_bfloat16 hsb[128][128];  // hs rows,  chunk c ^ (e&7)
  __shared__ __hip_bfloat16 hsT[128][128];  // hs^T, col' = (e + 8*(h&15))&127
  __shared__ __align__(16) float hp[2][H_];

  const int b = blockIdx.x;
  const int t = threadIdx.x;

  if (t < 256) {
    const int p = t >> 2;    // hh-pair: hh0 = 2p, hh1 = 2p+1
    const int sub = t & 3;   // k-quarter
    const int hh0 = 2 * p, hh1 = 2 * p + 1;

    // weights, rotated chunk order (matches hp read rotation)
    float wr0[32], wr1[32], wz0[32], wz1[32], wn0[32], wn1[32];
#pragma unroll
    for (int m = 0; m < 8; m++) {
      int c = (m + sub * 2) & 7;
      int kb = sub * 32 + c * 4;
      *(float4*)&wr0[m * 4] = *(const float4*)(w_hh + (size_t)hh0 * H_ + kb);
      *(float4*)&wr1[m * 4] = *(const float4*)(w_hh + (size_t)hh1 * H_ + kb);
      *(float4*)&wz0[m * 4] = *(const float4*)(w_hh + (size_t)(128 + hh0) * H_ + kb);
      *(float4*)&wz1[m * 4] = *(const float4*)(w_hh + (size_t)(128 + hh1) * H_ + kb);
      *(float4*)&wn0[m * 4] = *(const float4*)(w_hh + (size_t)(256 + hh0) * H_ + kb);
      *(float4*)&wn1[m * 4] = *(const float4*)(w_hh + (size_t)(256 + hh1) * H_ + kb);
    }

    const float* xgb = xg + (size_t)b * SDEC * G3;
    const float br0 = b_hh[hh0], br1 = b_hh[hh1];
    const float bz0 = b_hh[128 + hh0], bz1 = b_hh[128 + hh1];
    const float bn0 = b_hh[256 + hh0], bn1 = b_hh[256 + hh1];
    f32x2 cxr = *(const f32x2*)(xgb + hh0);
    f32x2 cxz = *(const f32x2*)(xgb + 128 + hh0);
    f32x2 cxn = *(const f32x2*)(xgb + 256 + hh0);
    f32x2 hc = *(const f32x2*)(h0 + (size_t)b * H_ + hh0);
    if (sub == 0) *(f32x2*)&hp[0][hh0] = hc;
    __hip_bfloat16* catbfb = cat_bf + (size_t)b * SDEC * 256;

    asm volatile("s_waitcnt lgkmcnt(0)" ::: "memory");
    __builtin_amdgcn_s_barrier();
    asm volatile("" ::: "memory");

    int cur = 0;
    for (int s8 = 0; s8 < 16; s8++) {
      uint hist[8];
#pragma unroll
      for (int si = 0; si < 8; si++) {
        const int s = s8 * 8 + si;
        f32x2 nxr = {0.f, 0.f}, nxz = {0.f, 0.f}, nxn = {0.f, 0.f};
        if (s + 1 < SDEC) {
          const float* xp = xgb + (size_t)(s + 1) * G3;
          nxr = *(const f32x2*)(xp + hh0);
          nxz = *(const f32x2*)(xp + 128 + hh0);
          nxn = *(const f32x2*)(xp + 256 + hh0);
        }
        f32x2 sr0_ = {0.f, 0.f}, sr1_ = {0.f, 0.f};
        f32x2 sz0_ = {0.f, 0.f}, sz1_ = {0.f, 0.f};
        f32x2 sn0_ = {0.f, 0.f}, sn1_ = {0.f, 0.f};
#pragma unroll
        for (int m = 0; m < 8; m++) {
          int c = (m + sub * 2) & 7;
          float4 hv = *(const float4*)&hp[cur][sub * 32 + c * 4];
          f32x2 h01 = {hv.x, hv.y}, h23 = {hv.z, hv.w};
          const f32x2* r0 = (const f32x2*)&wr0[m * 4];
          const f32x2* r1 = (const f32x2*)&wr1[m * 4];
          const f32x2* z0 = (const f32x2*)&wz0[m * 4];
          const f32x2* z1 = (const f32x2*)&wz1[m * 4];
          const f32x2* n0 = (const f32x2*)&wn0[m * 4];
          const f32x2* n1 = (const f32x2*)&wn1[m * 4];
          sr0_ += r0[0] * h01; sr0_ += r0[1] * h23;
          sr1_ += r1[0] * h01; sr1_ += r1[1] * h23;
          sz0_ += z0[0] * h01; sz0_ += z0[1] * h23;
          sz1_ += z1[0] * h01; sz1_ += z1[1] * h23;
          sn0_ += n0[0] * h01; sn0_ += n0[1] * h23;
          sn1_ += n1[0] * h01; sn1_ += n1[1] * h23;
        }
        float sr0 = quad_reduce(sr0_[0] + sr0_[1]);
        float sr1 = quad_reduce(sr1_[0] + sr1_[1]);
        float sz0 = quad_reduce(sz0_[0] + sz0_[1]);
        float sz1 = quad_reduce(sz1_[0] + sz1_[1]);
        float sn0 = quad_reduce(sn0_[0] + sn0_[1]);
        float sn1 = quad_reduce(sn1_[0] + sn1_[1]);

        float r0g = fast_sigmoid(cxr[0] + sr0 + br0);
        float z0g = fast_sigmoid(cxz[0] + sz0 + bz0);
        float n0g = fast_tanh(cxn[0] + r0g * (sn0 + bn0));
        float h0n = (1.f - z0g) * n0g + z0g * hc[0];
        float r1g = fast_sigmoid(cxr[1] + sr1 + br1);
        float z1g = fast_sigmoid(cxz[1] + sz1 + bz1);
        float n1g = fast_tanh(cxn[1] + r1g * (sn1 + bn1));
        float h1n = (1.f - z1g) * n1g + z1g * hc[1];
        hc[0] = h0n; hc[1] = h1n;

        union { __hip_bfloat16 h[2]; uint u; } pk2;
        pk2.h[0] = __float2bfloat16(h0n);
        pk2.h[1] = __float2bfloat16(h1n);
        hist[si] = pk2.u;
        if (sub == 0) {
          *(f32x2*)&hp[cur ^ 1][hh0] = hc;
          *(uint*)&ctb[s][((hh0 >> 3) ^ (s & 7)) * 8 + (hh0 & 7)] = pk2.u;
        }
        asm volatile("s_waitcnt lgkmcnt(0)" ::: "memory");
        __builtin_amdgcn_s_barrier();
        asm volatile("" ::: "memory");
        cur ^= 1;
        cxr = nxr; cxz = nxz; cxn = nxn;
      }
      // burst-store 8 rows of cat_bf (off the per-step critical path)
      if (sub == 0) {
#pragma unroll
        for (int si = 0; si < 8; si++)
          *(uint*)(catbfb + (size_t)(s8 * 8 + si) * 256 + hh0) = hist[si];
      }
    }
    if (sub == 0) *(f32x2*)(state_out + (size_t)b * H_ + hh0) = hc;
  } else {
    // idle waves: matching barrier sequence (1 pre-loop + SDEC in-loop)
    asm volatile("s_waitcnt lgkmcnt(0)" ::: "memory");
    __builtin_amdgcn_s_barrier();
    asm volatile("" ::: "memory");
    for (int s = 0; s < SDEC; s++) {
      asm volatile("s_waitcnt lgkmcnt(0)" ::: "memory");
      __builtin_amdgcn_s_barrier();
      asm volatile("" ::: "memory");
    }
  }

  // ================== fused attention (same block, batch b) ================
  const int w = t >> 6, l = t & 63;
  const int lr = l & 15, lk = l >> 4;
  const float* hsbase = hs + (size_t)b * SENC * H_;

  // stage hs (f32 -> bf16, swizzled rows)
  for (int i = t; i < 2048; i += 512) {
    int e = i >> 4, c = i & 15;
    float4 v0 = *(const float4*)(hsbase + e * H_ + c * 8);
    float4 v1 = *(const float4*)(hsbase + e * H_ + c * 8 + 4);
    union { __hip_bfloat16 h[8]; uint4 u; } pk;
    pk.h[0] = __float2bfloat16(v0.x); pk.h[1] = __float2bfloat16(v0.y);
    pk.h[2] = __float2bfloat16(v0.z); pk.h[3] = __float2bfloat16(v0.w);
    pk.h[4] = __float2bfloat16(v1.x); pk.h[5] = __float2bfloat16(v1.y);
    pk.h[6] = __float2bfloat16(v1.z); pk.h[7] = __float2bfloat16(v1.w);
    *(uint4*)&hsb[e][((c ^ (e & 7)) * 8)] = pk.u;
  }
  __syncthreads();

  // build rotated hs^T from hsb
  for (int i = t; i < 2048; i += 512) {
    int c = i >> 7, e = i & 127;
    uint4 v = *(const uint4*)&hsb[e][((c ^ (e & 7)) * 8)];
    const __hip_bfloat16* hv = (const __hip_bfloat16*)&v;
#pragma unroll
    for (int u = 0; u < 8; u++) {
      int h = c * 8 + u;
      int col = (e + 8 * (h & 15)) & 127;
      hsT[h][col] = hv[u];
    }
  }
  // A-fragments (ct rows) into registers before ctb is overlaid by P
  const int d = w * 16 + lr;
  bf16x8 afrag[4];
#pragma unroll
  for (int kt = 0; kt < 4; kt++)
    afrag[kt] = *(const bf16x8*)&ctb[d][(((kt * 4 + lk) ^ (lr & 7)) * 8)];
  __syncthreads();  // hsT ready; all ctb reads complete

  // phase 2: scores S[d][e]
  f32x4 acc[8];
#pragma unroll
  for (int et = 0; et < 8; et++) acc[et] = (f32x4){0.f, 0.f, 0.f, 0.f};
  __builtin_amdgcn_s_setprio(1);
#pragma unroll
  for (int et = 0; et < 8; et++) {
#pragma unroll
    for (int kt = 0; kt < 4; kt++) {
      bf16x8 bfrag =
          *(const bf16x8*)&hsb[et * 16 + lr][(((kt * 4 + lk) ^ (lr & 7)) * 8)];
      acc[et] =
          __builtin_amdgcn_mfma_f32_16x16x32_bf16(bfrag, afrag[kt], acc[et], 0, 0, 0);
    }
  }
  __builtin_amdgcn_s_setprio(0);

  // phase 3: softmax over e, in-register
  float mx = -1e30f;
#pragma unroll
  for (int et = 0; et < 8; et++)
    mx = fmaxf(mx, fmaxf(fmaxf(acc[et][0], acc[et][1]),
                         fmaxf(acc[et][2], acc[et][3])));
  mx = fmaxf(mx, __shfl_xor(mx, 16));
  mx = fmaxf(mx, __shfl_xor(mx, 32));
  float sum = 0.f;
#pragma unroll
  for (int et = 0; et < 8; et++) {
    acc[et][0] = __expf(acc[et][0] - mx);
    acc[et][1] = __expf(acc[et][1] - mx);
    acc[et][2] = __expf(acc[et][2] - mx);
    acc[et][3] = __expf(acc[et][3] - mx);
    sum += acc[et][0] + acc[et][1] + acc[et][2] + acc[et][3];
  }
  sum += __shfl_xor(sum, 16);
  sum += __shfl_xor(sum, 32);
  const float inv = 1.f / sum;

  // write P (bf16, into ctb space) + attw (f32)
  __hip_bfloat16 (*plds)[128] = ctb;
  float* aw = attw_out + (size_t)b * SENC * SDEC + d;
#pragma unroll
  for (int et = 0; et < 8; et++) {
    acc[et][0] *= inv; acc[et][1] *= inv;
    acc[et][2] *= inv; acc[et][3] *= inv;
    union { __hip_bfloat16 h[4]; uint2 u; } pk4;
    pk4.h[0] = __float2bfloat16(acc[et][0]);
    pk4.h[1] = __float2bfloat16(acc[et][1]);
    pk4.h[2] = __float2bfloat16(acc[et][2]);
    pk4.h[3] = __float2bfloat16(acc[et][3]);
    *(uint2*)&plds[d][(((et * 2 + (lk >> 1)) ^ (lr & 7)) * 8 + 4 * (lk & 1))] =
        pk4.u;
    const int e0 = et * 16 + lk * 4;
#pragma unroll
    for (int j = 0; j < 4; j++)
      aw[(size_t)(e0 + j) * SDEC] = acc[et][j];
  }
  __syncthreads();

  // phase 4: context c[d][h] = P @ hs
  bf16x8 pfrag[4];
#pragma unroll
  for (int f = 0; f < 4; f++)
    pfrag[f] = *(const bf16x8*)&plds[d][(((f * 4 + lk) ^ (lr & 7)) * 8)];
#pragma unroll
  for (int ht = 0; ht < 8; ht++) {
    f32x4 a2 = (f32x4){0.f, 0.f, 0.f, 0.f};
    __builtin_amdgcn_s_setprio(1);
#pragma unroll
    for (int kt = 0; kt < 4; kt++) {
      bf16x8 hfrag =
          *(const bf16x8*)&hsT[ht * 16 + lr][((kt * 32 + lk * 8 + 8 * lr) & 127)];
      a2 = __builtin_amdgcn_mfma_f32_16x16x32_bf16(hfrag, pfrag[kt], a2, 0, 0, 0);
    }
    __builtin_amdgcn_s_setprio(0);
    union { __hip_bfloat16 h[4]; uint2 u; } pk4;
    pk4.h[0] = __float2bfloat16(a2[0]);
    pk4.h[1] = __float2bfloat16(a2[1]);
    pk4.h[2] = __float2bfloat16(a2[2]);
    pk4.h[3] = __float2bfloat16(a2[3]);
    *(uint2*)(cat_bf + (size_t)(b * SDEC + d) * 256 + 128 + ht * 16 + lk * 4) =
        pk4.u;
  }
}

// ---------------------------------------------------------------------------
// Kernel 4: logits = cat @ w_out^T + b_out  (R8 structure verbatim)
// ---------------------------------------------------------------------------
__global__ __launch_bounds__(512) void k_gemm_mfma(
    const __hip_bfloat16* __restrict__ A, const __hip_bfloat16* __restrict__ Bw,
    const float* __restrict__ b_out, float* __restrict__ C) {
  constexpr int K = 256, N = V_, Kt = 32;
  alignas(16) __shared__ char smem[73728];  // 72 KB
  __hip_bfloat16 (*As)[4096] = (__hip_bfloat16(*)[4096])smem;            // [3][128*32]
  __hip_bfloat16 (*Bs)[8192] = (__hip_bfloat16(*)[8192])(smem + 24576);  // [3][256*32]
  float* tr = (float*)smem;  // epilogue: [64][260] padded f32 half-tile

  const int tid = threadIdx.x;
  const int w = tid >> 6, l = tid & 63;
  const int wr = w >> 2, wc = w & 3;       // 2M x 4N waves, each 64x64
  const int lr = l & 15, lk = l >> 4;
  const int lq = l >> 2, lc = l & 3;

  const int bid = blockIdx.x;
  const int wgid = (bid & 7) * 500 + (bid >> 3);
  const int mt = wgid & 31;
  const int nt = wgid >> 5;
  const int m0 = mt * 128, n0 = nt * 256;

  f32x4 acc[4][4];
#pragma unroll
  for (int m = 0; m < 4; m++)
#pragma unroll
    for (int n = 0; n < 4; n++) acc[m][n] = (f32x4){0.f, 0.f, 0.f, 0.f};

#define STAGE(buf, kk)                                                            \
  do {                                                                            \
    const __hip_bfloat16* gA = A + (size_t)(m0 + w * 16 + lq) * K + (kk) + lc * 8;\
    const __hip_bfloat16* gB0 = Bw + (size_t)(n0 + w * 32 + lq) * K + (kk) + lc * 8;\
    const __hip_bfloat16* gB1 = gB0 + (size_t)16 * K;                             \
    __builtin_amdgcn_global_load_lds((const GLOBAL_AS void*)gA,                   \
        (LDS_AS void*)(&As[buf][w * 512]), 16, 0, 0);                             \
    __builtin_amdgcn_global_load_lds((const GLOBAL_AS void*)gB0,                  \
        (LDS_AS void*)(&Bs[buf][w * 1024]), 16, 0, 0);                            \
    __builtin_amdgcn_global_load_lds((const GLOBAL_AS void*)gB1,                  \
        (LDS_AS void*)(&Bs[buf][w * 1024 + 512]), 16, 0, 0);                      \
  } while (0)

  STAGE(0, 0);
  STAGE(1, Kt);

#pragma unroll
  for (int t = 0; t < 8; ++t) {
    if (t < 7) asm volatile("s_waitcnt vmcnt(3)" ::: "memory");
    else       asm volatile("s_waitcnt vmcnt(0)" ::: "memory");
    __builtin_amdgcn_s_barrier();
    asm volatile("" ::: "memory");

    const int c = t % 3;
    bf16x8 af[4], bfr[4];
#pragma unroll
    for (int m = 0; m < 4; m++)
      af[m] = *(const bf16x8*)(const void*)(&As[c][(wr * 64 + m * 16 + lr) * Kt + lk * 8]);
#pragma unroll
    for (int n = 0; n < 4; n++)
      bfr[n] = *(const bf16x8*)(const void*)(&Bs[c][(wc * 64 + n * 16 + lr) * Kt + lk * 8]);

    if (t < 6) STAGE((t + 2) % 3, (t + 2) * Kt);

    __builtin_amdgcn_s_setprio(1);
#pragma unroll
    for (int m = 0; m < 4; m++)
#pragma unroll
      for (int n = 0; n < 4; n++)
        acc[m][n] = __builtin_amdgcn_mfma_f32_16x16x32_bf16(bfr[n], af[m], acc[m][n], 0, 0, 0);
    __builtin_amdgcn_s_setprio(0);
  }
#undef STAGE

  __syncthreads();
#pragma unroll
  for (int h = 0; h < 2; ++h) {
    if (wr == h) {
#pragma unroll
      for (int m = 0; m < 4; m++) {
#pragma unroll
        for (int n = 0; n < 4; n++) {
          const int row = m * 16 + lr;
          const int col = wc * 64 + n * 16 + lk * 4;
          const float4 bo = *(const float4*)(b_out + n0 + col);
          f32x4 v;
          v[0] = acc[m][n][0] + bo.x;
          v[1] = acc[m][n][1] + bo.y;
          v[2] = acc[m][n][2] + bo.z;
          v[3] = acc[m][n][3] + bo.w;
          *(f32x4*)&tr[row * 260 + col] = v;
        }
      }
    }
    __syncthreads();
#pragma unroll
    for (int i = 0; i < 8; ++i) {
      const int c2 = i * 512 + tid;
      const int row = c2 >> 6;
      const int off = (c2 & 63) * 4;
      f32x4 v = *(const f32x4*)&tr[row * 260 + off];
      __builtin_nontemporal_store(
          v, (f32x4*)(C + (size_t)(m0 + h * 64 + row) * N + n0 + off));
    }
    __syncthreads();
  }
}

// ---------------------------------------------------------------------------
extern "C" void kernel_launch(void* const* d_in, const int* in_sizes, int n_in,
                              void* d_out, int out_size, void* d_ws, size_t ws_size,
                              hipStream_t stream) {
  const int* seq = (const int*)d_in[0];
  const float* hs = (const float*)d_in[1];
  const float* h0 = (const float*)d_in[2];
  const float* emb = (const float*)d_in[3];
  const float* w_ih = (const float*)d_in[4];
  const float* w_hh = (const float*)d_in[5];
  const float* b_ih = (const float*)d_in[6];
  const float* b_hh = (const float*)d_in[7];
  const float* w_out = (const float*)d_in[8];
  const float* b_out = (const float*)d_in[9];

  float* out = (float*)d_out;
  float* logits = out;                          // 131,072,000 f32
  float* state = out + 131072000;               // 4,096 f32
  float* attw = out + 131072000 + 4096;         // 524,288 f32

  char* ws = (char*)d_ws;
  float* xg = (float*)ws;                              // 6,291,456 B
  __hip_bfloat16* cat_bf = (__hip_bfloat16*)(ws + 10485760);   // 2,097,152 B
  __hip_bfloat16* wout_bf = (__hip_bfloat16*)(ws + 12582912);  // 16,384,000 B

  k_embed_proj<<<256, 192, 0, stream>>>(seq, emb, w_ih, b_ih, xg);
  k_gru_attn_cvt<<<532, 512, 0, stream>>>(xg, h0, w_hh, b_hh, hs, cat_bf,
                                          state, attw, w_out, wout_bf);
  k_gemm_mfma<<<4000, 512, 0, stream>>>(cat_bf, wout_bf, b_out, logits);
}

// Round 16
// 250.186 us; speedup vs baseline: 1.1091x; 1.1091x over previous
//
#include <hip/hip_runtime.h>
#include <hip/hip_bf16.h>

#define B_    32
#define SDEC  128
#define SENC  128
#define V_    32000
#define E_    200
#define H_    128
#define G3    384   // 3*H

typedef __attribute__((ext_vector_type(8))) short bf16x8;
typedef __attribute__((ext_vector_type(4))) float f32x4;
typedef __attribute__((ext_vector_type(2))) float f32x2;

#define GLOBAL_AS __attribute__((address_space(1)))
#define LDS_AS    __attribute__((address_space(3)))

__device__ __forceinline__ float fast_sigmoid(float x) {
  return 1.f / (1.f + __expf(-x));
}
__device__ __forceinline__ float fast_tanh(float x) {
  float e2 = __expf(2.f * x);
  return 1.f - 2.f / (e2 + 1.f);
}
// butterfly sum over each aligned 4-lane quad, pure VALU (DPP quad_perm)
__device__ __forceinline__ float quad_reduce(float x) {
  int i = __builtin_bit_cast(int, x);
  int a = __builtin_amdgcn_mov_dpp(i, 0xB1, 0xF, 0xF, true);  // xor 1
  float s = x + __builtin_bit_cast(float, a);
  int j = __builtin_bit_cast(int, s);
  int c = __builtin_amdgcn_mov_dpp(j, 0x4E, 0xF, 0xF, true);  // xor 2
  return s + __builtin_bit_cast(float, c);
}

// ---------------------------------------------------------------------------
// Kernel 1: x = emb[seq]; xg = x @ w_ih^T + b_ih   -> xg [4096][384] f32
// ---------------------------------------------------------------------------
__global__ __launch_bounds__(192) void k_embed_proj(
    const int* __restrict__ seq, const float* __restrict__ emb,
    const float* __restrict__ w_ih, const float* __restrict__ b_ih,
    float* __restrict__ xg) {
  __shared__ __align__(16) float xs[16][E_];
  __shared__ int sidx[16];
  const int r0 = blockIdx.x * 16;
  const int t = threadIdx.x;
  if (t < 16) sidx[t] = seq[r0 + t];
  __syncthreads();
  for (int i = t; i < 800; i += 192) {
    int r = i / 50, c = i - r * 50;
    *(float4*)&xs[r][c * 4] =
        *(const float4*)(emb + (size_t)sidx[r] * E_ + c * 4);
  }
  __syncthreads();
  const int g0 = t, g1 = t + 192;
  float a0[16], a1[16];
#pragma unroll
  for (int r = 0; r < 16; r++) { a0[r] = 0.f; a1[r] = 0.f; }
  const float* w0 = w_ih + (size_t)g0 * E_;
  const float* w1 = w_ih + (size_t)g1 * E_;
  for (int k = 0; k < E_; k += 4) {
    float4 wv0 = *(const float4*)(w0 + k);
    float4 wv1 = *(const float4*)(w1 + k);
#pragma unroll
    for (int r = 0; r < 16; r++) {
      float4 xv = *(const float4*)&xs[r][k];
      a0[r] += wv0.x * xv.x + wv0.y * xv.y + wv0.z * xv.z + wv0.w * xv.w;
      a1[r] += wv1.x * xv.x + wv1.y * xv.y + wv1.z * xv.z + wv1.w * xv.w;
    }
  }
  const float b0 = b_ih[g0], b1 = b_ih[g1];
#pragma unroll
  for (int r = 0; r < 16; r++) {
    xg[(size_t)(r0 + r) * G3 + g0] = a0[r] + b0;
    xg[(size_t)(r0 + r) * G3 + g1] = a1[r] + b1;
  }
}

// ---------------------------------------------------------------------------
// Kernel 2: blocks 0..31  : GRU scan + fused MFMA attention (one batch each)
//           blocks 32..531: w_out f32->bf16, 4 ILP chunks each
// O=2 scan remap: 256 threads, thread = (hh-pair p = t>>2, k-quarter sub).
// Same rotated chunk order + quad butterfly as R8 -> bit-identical numerics.
// ---------------------------------------------------------------------------
__global__ __launch_bounds__(512) void k_gru_attn_cvt(
    const float* __restrict__ xg, const float* __restrict__ h0,
    const float* __restrict__ w_hh, const float* __restrict__ b_hh,
    const float* __restrict__ hs, __hip_bfloat16* __restrict__ cat_bf,
    float* __restrict__ state_out, float* __restrict__ attw_out,
    const float* __restrict__ w_out, __hip_bfloat16* __restrict__ wout_bf) {
  if (blockIdx.x >= 32) {
    const int base = (blockIdx.x - 32) * 4;
#pragma unroll
    for (int j = 0; j < 4; j++) {
      int idx = ((base + j) * 512 + threadIdx.x) * 8;
      float4 a = *(const float4*)(w_out + idx);
      float4 c = *(const float4*)(w_out + idx + 4);
      union { __hip_bfloat16 h[8]; uint4 v; } p;
      p.h[0] = __float2bfloat16(a.x); p.h[1] = __float2bfloat16(a.y);
      p.h[2] = __float2bfloat16(a.z); p.h[3] = __float2bfloat16(a.w);
      p.h[4] = __float2bfloat16(c.x); p.h[5] = __float2bfloat16(c.y);
      p.h[6] = __float2bfloat16(c.z); p.h[7] = __float2bfloat16(c.w);
      *(uint4*)(wout_bf + idx) = p.v;
    }
    return;
  }

  __shared__ __hip_bfloat16 ctb[128][128];  // GRU out (scan) -> P (phase 4)
  __shared__ __hip_bfloat16 hsb[128][128];  // hs rows,  chunk c ^ (e&7)
  __shared__ __hip_bfloat16 hsT[128][128];  // hs^T, col' = (e + 8*(h&15))&127
  __shared__ __align__(16) float hp[2][H_];

  const int b = blockIdx.x;
  const int t = threadIdx.x;

  if (t < 256) {
    const int p = t >> 2;    // hh-pair: hh0 = 2p, hh1 = 2p+1
    const int sub = t & 3;   // k-quarter
    const int hh0 = 2 * p, hh1 = 2 * p + 1;

    // weights, rotated chunk order (matches hp read rotation)
    float wr0[32], wr1[32], wz0[32], wz1[32], wn0[32], wn1[32];
#pragma unroll
    for (int m = 0; m < 8; m++) {
      int c = (m + sub * 2) & 7;
      int kb = sub * 32 + c * 4;
      *(float4*)&wr0[m * 4] = *(const float4*)(w_hh + (size_t)hh0 * H_ + kb);
      *(float4*)&wr1[m * 4] = *(const float4*)(w_hh + (size_t)hh1 * H_ + kb);
      *(float4*)&wz0[m * 4] = *(const float4*)(w_hh + (size_t)(128 + hh0) * H_ + kb);
      *(float4*)&wz1[m * 4] = *(const float4*)(w_hh + (size_t)(128 + hh1) * H_ + kb);
      *(float4*)&wn0[m * 4] = *(const float4*)(w_hh + (size_t)(256 + hh0) * H_ + kb);
      *(float4*)&wn1[m * 4] = *(const float4*)(w_hh + (size_t)(256 + hh1) * H_ + kb);
    }

    const float* xgb = xg + (size_t)b * SDEC * G3;
    const float br0 = b_hh[hh0], br1 = b_hh[hh1];
    const float bz0 = b_hh[128 + hh0], bz1 = b_hh[128 + hh1];
    const float bn0 = b_hh[256 + hh0], bn1 = b_hh[256 + hh1];
    f32x2 cxr = *(const f32x2*)(xgb + hh0);
    f32x2 cxz = *(const f32x2*)(xgb + 128 + hh0);
    f32x2 cxn = *(const f32x2*)(xgb + 256 + hh0);
    f32x2 hc = *(const f32x2*)(h0 + (size_t)b * H_ + hh0);
    if (sub == 0) *(f32x2*)&hp[0][hh0] = hc;
    __hip_bfloat16* catbfb = cat_bf + (size_t)b * SDEC * 256;

    asm volatile("s_waitcnt lgkmcnt(0)" ::: "memory");
    __builtin_amdgcn_s_barrier();
    asm volatile("" ::: "memory");

    int cur = 0;
    for (int s = 0; s < SDEC; s++) {
      f32x2 nxr = {0.f, 0.f}, nxz = {0.f, 0.f}, nxn = {0.f, 0.f};
      if (s + 1 < SDEC) {
        const float* xp = xgb + (size_t)(s + 1) * G3;
        nxr = *(const f32x2*)(xp + hh0);
        nxz = *(const f32x2*)(xp + 128 + hh0);
        nxn = *(const f32x2*)(xp + 256 + hh0);
      }
      f32x2 sr0_ = {0.f, 0.f}, sr1_ = {0.f, 0.f};
      f32x2 sz0_ = {0.f, 0.f}, sz1_ = {0.f, 0.f};
      f32x2 sn0_ = {0.f, 0.f}, sn1_ = {0.f, 0.f};
#pragma unroll
      for (int m = 0; m < 8; m++) {
        int c = (m + sub * 2) & 7;
        float4 hv = *(const float4*)&hp[cur][sub * 32 + c * 4];
        f32x2 h01 = {hv.x, hv.y}, h23 = {hv.z, hv.w};
        const f32x2* r0 = (const f32x2*)&wr0[m * 4];
        const f32x2* r1 = (const f32x2*)&wr1[m * 4];
        const f32x2* z0 = (const f32x2*)&wz0[m * 4];
        const f32x2* z1 = (const f32x2*)&wz1[m * 4];
        const f32x2* n0 = (const f32x2*)&wn0[m * 4];
        const f32x2* n1 = (const f32x2*)&wn1[m * 4];
        sr0_ += r0[0] * h01; sr0_ += r0[1] * h23;
        sr1_ += r1[0] * h01; sr1_ += r1[1] * h23;
        sz0_ += z0[0] * h01; sz0_ += z0[1] * h23;
        sz1_ += z1[0] * h01; sz1_ += z1[1] * h23;
        sn0_ += n0[0] * h01; sn0_ += n0[1] * h23;
        sn1_ += n1[0] * h01; sn1_ += n1[1] * h23;
      }
      float sr0 = quad_reduce(sr0_[0] + sr0_[1]);
      float sr1 = quad_reduce(sr1_[0] + sr1_[1]);
      float sz0 = quad_reduce(sz0_[0] + sz0_[1]);
      float sz1 = quad_reduce(sz1_[0] + sz1_[1]);
      float sn0 = quad_reduce(sn0_[0] + sn0_[1]);
      float sn1 = quad_reduce(sn1_[0] + sn1_[1]);

      // all 4 lanes compute both activations (no divergence, hc in regs)
      float r0g = fast_sigmoid(cxr[0] + sr0 + br0);
      float z0g = fast_sigmoid(cxz[0] + sz0 + bz0);
      float n0g = fast_tanh(cxn[0] + r0g * (sn0 + bn0));
      float h0n = (1.f - z0g) * n0g + z0g * hc[0];
      float r1g = fast_sigmoid(cxr[1] + sr1 + br1);
      float z1g = fast_sigmoid(cxz[1] + sz1 + bz1);
      float n1g = fast_tanh(cxn[1] + r1g * (sn1 + bn1));
      float h1n = (1.f - z1g) * n1g + z1g * hc[1];
      hc[0] = h0n; hc[1] = h1n;
      if (sub == 0) {
        *(f32x2*)&hp[cur ^ 1][hh0] = hc;
        union { __hip_bfloat16 h[2]; uint u; } pk2;
        pk2.h[0] = __float2bfloat16(h0n);
        pk2.h[1] = __float2bfloat16(h1n);
        *(uint*)(catbfb + (size_t)s * 256 + hh0) = pk2.u;
        // ctb fragment layout: hh0,hh1 share chunk (bit0 differs only)
        *(uint*)&ctb[s][((hh0 >> 3) ^ (s & 7)) * 8 + (hh0 & 7)] = pk2.u;
      }
      asm volatile("s_waitcnt lgkmcnt(0)" ::: "memory");
      __builtin_amdgcn_s_barrier();
      asm volatile("" ::: "memory");
      cur ^= 1;
      cxr = nxr; cxz = nxz; cxn = nxn;
    }
    if (sub == 0) *(f32x2*)(state_out + (size_t)b * H_ + hh0) = hc;
  } else {
    // idle waves: matching barrier sequence (1 pre-loop + SDEC in-loop)
    asm volatile("s_waitcnt lgkmcnt(0)" ::: "memory");
    __builtin_amdgcn_s_barrier();
    asm volatile("" ::: "memory");
    for (int s = 0; s < SDEC; s++) {
      asm volatile("s_waitcnt lgkmcnt(0)" ::: "memory");
      __builtin_amdgcn_s_barrier();
      asm volatile("" ::: "memory");
    }
  }

  // ================== fused attention (same block, batch b) ================
  const int w = t >> 6, l = t & 63;
  const int lr = l & 15, lk = l >> 4;
  const float* hsbase = hs + (size_t)b * SENC * H_;

  // stage hs (f32 -> bf16, swizzled rows)
  for (int i = t; i < 2048; i += 512) {
    int e = i >> 4, c = i & 15;
    float4 v0 = *(const float4*)(hsbase + e * H_ + c * 8);
    float4 v1 = *(const float4*)(hsbase + e * H_ + c * 8 + 4);
    union { __hip_bfloat16 h[8]; uint4 u; } pk;
    pk.h[0] = __float2bfloat16(v0.x); pk.h[1] = __float2bfloat16(v0.y);
    pk.h[2] = __float2bfloat16(v0.z); pk.h[3] = __float2bfloat16(v0.w);
    pk.h[4] = __float2bfloat16(v1.x); pk.h[5] = __float2bfloat16(v1.y);
    pk.h[6] = __float2bfloat16(v1.z); pk.h[7] = __float2bfloat16(v1.w);
    *(uint4*)&hsb[e][((c ^ (e & 7)) * 8)] = pk.u;
  }
  __syncthreads();

  // build rotated hs^T from hsb
  for (int i = t; i < 2048; i += 512) {
    int c = i >> 7, e = i & 127;
    uint4 v = *(const uint4*)&hsb[e][((c ^ (e & 7)) * 8)];
    const __hip_bfloat16* hv = (const __hip_bfloat16*)&v;
#pragma unroll
    for (int u = 0; u < 8; u++) {
      int h = c * 8 + u;
      int col = (e + 8 * (h & 15)) & 127;
      hsT[h][col] = hv[u];
    }
  }
  // A-fragments (ct rows) into registers before ctb is overlaid by P
  const int d = w * 16 + lr;
  bf16x8 afrag[4];
#pragma unroll
  for (int kt = 0; kt < 4; kt++)
    afrag[kt] = *(const bf16x8*)&ctb[d][(((kt * 4 + lk) ^ (lr & 7)) * 8)];
  __syncthreads();  // hsT ready; all ctb reads complete

  // phase 2: scores S[d][e]
  f32x4 acc[8];
#pragma unroll
  for (int et = 0; et < 8; et++) acc[et] = (f32x4){0.f, 0.f, 0.f, 0.f};
  __builtin_amdgcn_s_setprio(1);
#pragma unroll
  for (int et = 0; et < 8; et++) {
#pragma unroll
    for (int kt = 0; kt < 4; kt++) {
      bf16x8 bfrag =
          *(const bf16x8*)&hsb[et * 16 + lr][(((kt * 4 + lk) ^ (lr & 7)) * 8)];
      acc[et] =
          __builtin_amdgcn_mfma_f32_16x16x32_bf16(bfrag, afrag[kt], acc[et], 0, 0, 0);
    }
  }
  __builtin_amdgcn_s_setprio(0);

  // phase 3: softmax over e, in-register
  float mx = -1e30f;
#pragma unroll
  for (int et = 0; et < 8; et++)
    mx = fmaxf(mx, fmaxf(fmaxf(acc[et][0], acc[et][1]),
                         fmaxf(acc[et][2], acc[et][3])));
  mx = fmaxf(mx, __shfl_xor(mx, 16));
  mx = fmaxf(mx, __shfl_xor(mx, 32));
  float sum = 0.f;
#pragma unroll
  for (int et = 0; et < 8; et++) {
    acc[et][0] = __expf(acc[et][0] - mx);
    acc[et][1] = __expf(acc[et][1] - mx);
    acc[et][2] = __expf(acc[et][2] - mx);
    acc[et][3] = __expf(acc[et][3] - mx);
    sum += acc[et][0] + acc[et][1] + acc[et][2] + acc[et][3];
  }
  sum += __shfl_xor(sum, 16);
  sum += __shfl_xor(sum, 32);
  const float inv = 1.f / sum;

  // write P (bf16, into ctb space) + attw (f32)
  __hip_bfloat16 (*plds)[128] = ctb;
  float* aw = attw_out + (size_t)b * SENC * SDEC + d;
#pragma unroll
  for (int et = 0; et < 8; et++) {
    acc[et][0] *= inv; acc[et][1] *= inv;
    acc[et][2] *= inv; acc[et][3] *= inv;
    union { __hip_bfloat16 h[4]; uint2 u; } pk4;
    pk4.h[0] = __float2bfloat16(acc[et][0]);
    pk4.h[1] = __float2bfloat16(acc[et][1]);
    pk4.h[2] = __float2bfloat16(acc[et][2]);
    pk4.h[3] = __float2bfloat16(acc[et][3]);
    *(uint2*)&plds[d][(((et * 2 + (lk >> 1)) ^ (lr & 7)) * 8 + 4 * (lk & 1))] =
        pk4.u;
    const int e0 = et * 16 + lk * 4;
#pragma unroll
    for (int j = 0; j < 4; j++)
      aw[(size_t)(e0 + j) * SDEC] = acc[et][j];
  }
  __syncthreads();

  // phase 4: context c[d][h] = P @ hs
  bf16x8 pfrag[4];
#pragma unroll
  for (int f = 0; f < 4; f++)
    pfrag[f] = *(const bf16x8*)&plds[d][(((f * 4 + lk) ^ (lr & 7)) * 8)];
#pragma unroll
  for (int ht = 0; ht < 8; ht++) {
    f32x4 a2 = (f32x4){0.f, 0.f, 0.f, 0.f};
    __builtin_amdgcn_s_setprio(1);
#pragma unroll
    for (int kt = 0; kt < 4; kt++) {
      bf16x8 hfrag =
          *(const bf16x8*)&hsT[ht * 16 + lr][((kt * 32 + lk * 8 + 8 * lr) & 127)];
      a2 = __builtin_amdgcn_mfma_f32_16x16x32_bf16(hfrag, pfrag[kt], a2, 0, 0, 0);
    }
    __builtin_amdgcn_s_setprio(0);
    union { __hip_bfloat16 h[4]; uint2 u; } pk4;
    pk4.h[0] = __float2bfloat16(a2[0]);
    pk4.h[1] = __float2bfloat16(a2[1]);
    pk4.h[2] = __float2bfloat16(a2[2]);
    pk4.h[3] = __float2bfloat16(a2[3]);
    *(uint2*)(cat_bf + (size_t)(b * SDEC + d) * 256 + 128 + ht * 16 + lk * 4) =
        pk4.u;
  }
}

// ---------------------------------------------------------------------------
// Kernel 4: logits = cat @ w_out^T + b_out  (R8 structure verbatim)
// ---------------------------------------------------------------------------
__global__ __launch_bounds__(512) void k_gemm_mfma(
    const __hip_bfloat16* __restrict__ A, const __hip_bfloat16* __restrict__ Bw,
    const float* __restrict__ b_out, float* __restrict__ C) {
  constexpr int K = 256, N = V_, Kt = 32;
  alignas(16) __shared__ char smem[73728];  // 72 KB
  __hip_bfloat16 (*As)[4096] = (__hip_bfloat16(*)[4096])smem;            // [3][128*32]
  __hip_bfloat16 (*Bs)[8192] = (__hip_bfloat16(*)[8192])(smem + 24576);  // [3][256*32]
  float* tr = (float*)smem;  // epilogue: [64][260] padded f32 half-tile

  const int tid = threadIdx.x;
  const int w = tid >> 6, l = tid & 63;
  const int wr = w >> 2, wc = w & 3;       // 2M x 4N waves, each 64x64
  const int lr = l & 15, lk = l >> 4;
  const int lq = l >> 2, lc = l & 3;

  const int bid = blockIdx.x;
  const int wgid = (bid & 7) * 500 + (bid >> 3);
  const int mt = wgid & 31;
  const int nt = wgid >> 5;
  const int m0 = mt * 128, n0 = nt * 256;

  f32x4 acc[4][4];
#pragma unroll
  for (int m = 0; m < 4; m++)
#pragma unroll
    for (int n = 0; n < 4; n++) acc[m][n] = (f32x4){0.f, 0.f, 0.f, 0.f};

#define STAGE(buf, kk)                                                            \
  do {                                                                            \
    const __hip_bfloat16* gA = A + (size_t)(m0 + w * 16 + lq) * K + (kk) + lc * 8;\
    const __hip_bfloat16* gB0 = Bw + (size_t)(n0 + w * 32 + lq) * K + (kk) + lc * 8;\
    const __hip_bfloat16* gB1 = gB0 + (size_t)16 * K;                             \
    __builtin_amdgcn_global_load_lds((const GLOBAL_AS void*)gA,                   \
        (LDS_AS void*)(&As[buf][w * 512]), 16, 0, 0);                             \
    __builtin_amdgcn_global_load_lds((const GLOBAL_AS void*)gB0,                  \
        (LDS_AS void*)(&Bs[buf][w * 1024]), 16, 0, 0);                            \
    __builtin_amdgcn_global_load_lds((const GLOBAL_AS void*)gB1,                  \
        (LDS_AS void*)(&Bs[buf][w * 1024 + 512]), 16, 0, 0);                      \
  } while (0)

  STAGE(0, 0);
  STAGE(1, Kt);

#pragma unroll
  for (int t = 0; t < 8; ++t) {
    if (t < 7) asm volatile("s_waitcnt vmcnt(3)" ::: "memory");
    else       asm volatile("s_waitcnt vmcnt(0)" ::: "memory");
    __builtin_amdgcn_s_barrier();
    asm volatile("" ::: "memory");

    const int c = t % 3;
    bf16x8 af[4], bfr[4];
#pragma unroll
    for (int m = 0; m < 4; m++)
      af[m] = *(const bf16x8*)(const void*)(&As[c][(wr * 64 + m * 16 + lr) * Kt + lk * 8]);
#pragma unroll
    for (int n = 0; n < 4; n++)
      bfr[n] = *(const bf16x8*)(const void*)(&Bs[c][(wc * 64 + n * 16 + lr) * Kt + lk * 8]);

    if (t < 6) STAGE((t + 2) % 3, (t + 2) * Kt);

    __builtin_amdgcn_s_setprio(1);
#pragma unroll
    for (int m = 0; m < 4; m++)
#pragma unroll
      for (int n = 0; n < 4; n++)
        acc[m][n] = __builtin_amdgcn_mfma_f32_16x16x32_bf16(bfr[n], af[m], acc[m][n], 0, 0, 0);
    __builtin_amdgcn_s_setprio(0);
  }
#undef STAGE

  __syncthreads();
#pragma unroll
  for (int h = 0; h < 2; ++h) {
    if (wr == h) {
#pragma unroll
      for (int m = 0; m < 4; m++) {
#pragma unroll
        for (int n = 0; n < 4; n++) {
          const int row = m * 16 + lr;
          const int col = wc * 64 + n * 16 + lk * 4;
          const float4 bo = *(const float4*)(b_out + n0 + col);
          f32x4 v;
          v[0] = acc[m][n][0] + bo.x;
          v[1] = acc[m][n][1] + bo.y;
          v[2] = acc[m][n][2] + bo.z;
          v[3] = acc[m][n][3] + bo.w;
          *(f32x4*)&tr[row * 260 + col] = v;
        }
      }
    }
    __syncthreads();
#pragma unroll
    for (int i = 0; i < 8; ++i) {
      const int c2 = i * 512 + tid;
      const int row = c2 >> 6;
      const int off = (c2 & 63) * 4;
      f32x4 v = *(const f32x4*)&tr[row * 260 + off];
      __builtin_nontemporal_store(
          v, (f32x4*)(C + (size_t)(m0 + h * 64 + row) * N + n0 + off));
    }
    __syncthreads();
  }
}

// ---------------------------------------------------------------------------
extern "C" void kernel_launch(void* const* d_in, const int* in_sizes, int n_in,
                              void* d_out, int out_size, void* d_ws, size_t ws_size,
                              hipStream_t stream) {
  const int* seq = (const int*)d_in[0];
  const float* hs = (const float*)d_in[1];
  const float* h0 = (const float*)d_in[2];
  const float* emb = (const float*)d_in[3];
  const float* w_ih = (const float*)d_in[4];
  const float* w_hh = (const float*)d_in[5];
  const float* b_ih = (const float*)d_in[6];
  const float* b_hh = (const float*)d_in[7];
  const float* w_out = (const float*)d_in[8];
  const float* b_out = (const float*)d_in[9];

  float* out = (float*)d_out;
  float* logits = out;                          // 131,072,000 f32
  float* state = out + 131072000;               // 4,096 f32
  float* attw = out + 131072000 + 4096;         // 524,288 f32

  char* ws = (char*)d_ws;
  float* xg = (float*)ws;                              // 6,291,456 B
  __hip_bfloat16* cat_bf = (__hip_bfloat16*)(ws + 10485760);   // 2,097,152 B
  __hip_bfloat16* wout_bf = (__hip_bfloat16*)(ws + 12582912);  // 16,384,000 B

  k_embed_proj<<<256, 192, 0, stream>>>(seq, emb, w_ih, b_ih, xg);
  k_gru_attn_cvt<<<532, 512, 0, stream>>>(xg, h0, w_hh, b_hh, hs, cat_bf,
                                          state, attw, w_out, wout_bf);
  k_gemm_mfma<<<4000, 512, 0, stream>>>(cat_bf, wout_bf, b_out, logits);
}